// Round 7
// baseline (65.409 us; speedup 1.0000x reference)
//
#include <hip/hip_runtime.h>
#include <hip/hip_bf16.h>

#define ALPHA 0.2f
#define LOG2E 1.4426950408889634f

typedef __attribute__((ext_vector_type(8))) short bf16x8;
typedef __attribute__((ext_vector_type(4))) float f32x4;
typedef __attribute__((ext_vector_type(4))) int i32x4;

__device__ __forceinline__ int cvt_pk_bf16(float lo, float hi) {
    int r;
    asm("v_cvt_pk_bf16_f32 %0, %1, %2" : "=v"(r) : "v"(lo), "v"(hi));
    return r;
}

// async global->LDS, 16B per lane; LDS dest = wave-uniform base + lane*16
__device__ __forceinline__ void stage16(const void* g, void* l) {
    __builtin_amdgcn_global_load_lds(
        (const __attribute__((address_space(1))) void*)g,
        (__attribute__((address_space(3))) void*)l, 16, 0, 0);
}

// ---------------------------------------------------------------------------
// Kernel A (verified, round-5 verbatim): Wh = h @ W (fp32), si2/sj2 scaled by
// log2e, WhT = bf16(Wh)^T o-major [b][64][2048]. 512 blocks x 256 threads.
// ---------------------------------------------------------------------------
__global__ __launch_bounds__(256) void gat_precompute(
    const float* __restrict__ h, const float* __restrict__ W,
    const float* __restrict__ a, unsigned short* __restrict__ WhT,
    float* __restrict__ si2, float* __restrict__ sj2)
{
    __shared__ float h_lds[32][128];
    __shared__ float wh_lds[32][65];   // +1 pad
    const int tid  = threadIdx.x;
    const int lane = tid & 63;
    const int wave = tid >> 6;
    const long long row0 = (long long)blockIdx.x * 32;

    {
        const float4* s4 = (const float4*)(h + row0 * 128);
        #pragma unroll
        for (int i = 0; i < 4; ++i) {
            int idx = tid + i * 256;
            float4 v = s4[idx];
            *(float4*)&h_lds[idx >> 5][(idx & 31) * 4] = v;
        }
    }
    __syncthreads();

    const float a1 = a[lane];
    const float a2 = a[64 + lane];
    float acc[8];
    #pragma unroll
    for (int r = 0; r < 8; ++r) acc[r] = 0.0f;

    for (int f = 0; f < 128; f += 4) {
        const float w0 = W[(f+0)*64 + lane];
        const float w1 = W[(f+1)*64 + lane];
        const float w2 = W[(f+2)*64 + lane];
        const float w3 = W[(f+3)*64 + lane];
        #pragma unroll
        for (int r = 0; r < 8; ++r) {
            const float4 hv = *(const float4*)&h_lds[wave*8 + r][f];
            acc[r] = fmaf(hv.x, w0, acc[r]);
            acc[r] = fmaf(hv.y, w1, acc[r]);
            acc[r] = fmaf(hv.z, w2, acc[r]);
            acc[r] = fmaf(hv.w, w3, acc[r]);
        }
    }

    #pragma unroll
    for (int r = 0; r < 8; ++r) {
        const int rr = wave*8 + r;
        wh_lds[rr][lane] = acc[r];
        float s1 = acc[r] * a1;
        float s2 = acc[r] * a2;
        #pragma unroll
        for (int off = 32; off > 0; off >>= 1) {
            s1 += __shfl_xor(s1, off);
            s2 += __shfl_xor(s2, off);
        }
        if (lane == 0) {
            si2[row0 + rr] = s1 * LOG2E;
            sj2[row0 + rr] = s2 * LOG2E;
        }
    }
    __syncthreads();

    const long long b  = row0 >> 11;
    const int n0 = (int)(row0 & 2047);
    const int o  = tid >> 2;
    const int c0 = (tid & 3) * 8;
    i32x4 pk;
    #pragma unroll
    for (int k = 0; k < 4; ++k)
        pk[k] = cvt_pk_bf16(wh_lds[c0 + 2*k][o], wh_lds[c0 + 2*k + 1][o]);
    *(i32x4*)(WhT + (b*64 + o)*2048 + n0 + c0) = pk;
}

// ---------------------------------------------------------------------------
// Kernel P: pack adj (0/1 int32) -> bitmask pk[b][granule g][n] (u64 = j bits
// g*64..g*64+63 of row n). Pure barrier-free stream: coalesced 256B loads,
// __ballot (64-bit), one predicated keep, coalesced 256B stores.
// Grid 512 = 8 b x 64 row-chunks of 32; 4 waves x 8 granules each.
// ---------------------------------------------------------------------------
__global__ __launch_bounds__(256) void gat_pack(
    const int* __restrict__ adj, unsigned long long* __restrict__ pk)
{
    const int tid  = threadIdx.x;
    const int lane = tid & 63;
    const int wave = tid >> 6;
    const int b    = blockIdx.x >> 6;
    const int n0   = (blockIdx.x & 63) << 5;          // 32 rows
    const long long base = ((long long)b*2048 + n0) * 2048;

    #pragma unroll
    for (int gi = 0; gi < 8; ++gi) {
        const int g = wave*8 + gi;
        const int* src = adj + base + g*64 + lane;
        unsigned long long mine = 0;
        #pragma unroll 8
        for (int r = 0; r < 32; ++r) {
            const unsigned long long bal = __ballot(src[(long long)r*2048] > 0);
            if (lane == r) mine = bal;
        }
        if (lane < 32)
            pk[((long long)b*32 + g)*2048 + n0 + lane] = mine;
    }
}

// ---------------------------------------------------------------------------
// Kernel B: fused masked-softmax attention (round-5 structure, adj replaced
// by 1 u64 bitmask load per lane per step). Block = (b, 32 i-rows); 4 waves:
// (wave&1)=row-group, (wave>>1)=j-half; 16 __syncthreads-double-buffered
// steps of 64 j per half. Only WhT is LDS-staged now (2 x 16KB).
// p = exp2(max(Ci+sj, 0.2*sj+Di)) * bit, fixed row max (lrelu monotone).
// ---------------------------------------------------------------------------
__global__ __launch_bounds__(256) void gat_attention(
    const unsigned long long* __restrict__ pk,
    const unsigned short* __restrict__ WhT,
    const float* __restrict__ si2, const float* __restrict__ sj2,
    float* __restrict__ out)
{
    __shared__ char ldsbuf[33024];   // [2][wh 16K] + lb 256B @32768
    const int tid  = threadIdx.x;
    const int lane = tid & 63;
    const int wave = tid >> 6;
    const int bid  = blockIdx.x;
    const int b    = bid >> 6;
    const int i0   = (bid & 63) << 5;   // *32
    const int arow = lane & 15;
    const int g    = lane >> 4;
    const int half = wave >> 1;
    const int rgrp = wave & 1;
    const long long bN = (long long)b * 2048;

    // ---- WhT staging sources (round-5 verbatim; inverse swizzle on SOURCE,
    //      linear dest; read-side applies the same XOR) ----
    const unsigned short* wsrc[4];
    #pragma unroll
    for (int rd = 0; rd < 4; ++rd) {
        int U  = wave*256 + rd*64 + lane;
        int hf = U >> 9;
        int o  = (U & 511) >> 3;
        int pu = U & 7;
        wsrc[rd] = WhT + ((long long)b*64 + o)*2048 + hf*1024
                       + ((pu ^ (o & 7)) * 8);
    }

    // ---- per-batch sjmax (block-redundant, once) ----
    const float* sjb = sj2 + bN;
    float mx = -INFINITY;
    #pragma unroll 4
    for (int i = 0; i < 32; ++i) mx = fmaxf(mx, sjb[lane + i*64]);
    #pragma unroll
    for (int off = 32; off > 0; off >>= 1) mx = fmaxf(mx, __shfl_xor(mx, off));

    const float si_r = si2[bN + i0 + rgrp*16 + arow];
    const float u0f  = si_r + mx;
    const float m2   = fmaxf(u0f, ALPHA * u0f);     // fixed row max (log2 dom)
    const float Ci   = si_r - m2;
    const float Di   = ALPHA * si_r - m2;
    const int   rr   = rgrp*16 + arow;

    // bitmask pointer: pk[b][g16][i0+rr], g16 = half*16 + st
    const unsigned long long* pkb = pk + ((long long)b*32)*2048 + i0 + rr
                                       + (long long)half*16*2048;

    f32x4 accf[4];
    #pragma unroll
    for (int ob = 0; ob < 4; ++ob) accf[ob] = (f32x4){0.f,0.f,0.f,0.f};
    f32x4 accl = (f32x4){0.f,0.f,0.f,0.f};
    bf16x8 ones;
    #pragma unroll
    for (int k = 0; k < 8; ++k) ones[k] = (short)0x3F80;

    #define STAGE(S, STEP) { \
        const int ja = (STEP) * 64; \
        char* wb_ = ldsbuf + (S)*16384 + wave*4096; \
        stage16(wsrc[0] + ja, wb_ + 0*1024); \
        stage16(wsrc[1] + ja, wb_ + 1*1024); \
        stage16(wsrc[2] + ja, wb_ + 2*1024); \
        stage16(wsrc[3] + ja, wb_ + 3*1024); \
    }

    #define KKBODY(KK) { \
        const int ws = ((KK)*4 + g) ^ (arow & 7); \
        const bf16x8 bf0 = *(const bf16x8*)(wb0 + (( 0 + arow)*8 + ws)*16); \
        const bf16x8 bf1 = *(const bf16x8*)(wb0 + ((16 + arow)*8 + ws)*16); \
        const bf16x8 bf2 = *(const bf16x8*)(wb0 + ((32 + arow)*8 + ws)*16); \
        const bf16x8 bf3 = *(const bf16x8*)(wb0 + ((48 + arow)*8 + ws)*16); \
        const unsigned mb = ((unsigned)(bits >> ((KK)*32)) >> (g*8)) & 0xffu; \
        const float* sjp = sjb + half*1024 + j0 + (KK)*32 + g*8; \
        const f32x4 S0 = *(const f32x4*)(sjp); \
        const f32x4 S1 = *(const f32x4*)(sjp + 4); \
        float p[8]; \
        _Pragma("unroll") \
        for (int e = 0; e < 4; ++e) { \
            float pe = __builtin_amdgcn_exp2f( \
                fmaxf(Ci + S0[e], fmaf(ALPHA, S0[e], Di))); \
            p[e] = (mb & (1u << e)) ? pe : 0.0f; \
        } \
        _Pragma("unroll") \
        for (int e = 0; e < 4; ++e) { \
            float pe = __builtin_amdgcn_exp2f( \
                fmaxf(Ci + S1[e], fmaf(ALPHA, S1[e], Di))); \
            p[4+e] = (mb & (1u << (4+e))) ? pe : 0.0f; \
        } \
        i32x4 pk_; \
        pk_[0] = cvt_pk_bf16(p[0], p[1]); \
        pk_[1] = cvt_pk_bf16(p[2], p[3]); \
        pk_[2] = cvt_pk_bf16(p[4], p[5]); \
        pk_[3] = cvt_pk_bf16(p[6], p[7]); \
        const bf16x8 pa = __builtin_bit_cast(bf16x8, pk_); \
        accl    = __builtin_amdgcn_mfma_f32_16x16x32_bf16(pa, ones, accl, 0, 0, 0); \
        accf[0] = __builtin_amdgcn_mfma_f32_16x16x32_bf16(pa, bf0, accf[0], 0, 0, 0); \
        accf[1] = __builtin_amdgcn_mfma_f32_16x16x32_bf16(pa, bf1, accf[1], 0, 0, 0); \
        accf[2] = __builtin_amdgcn_mfma_f32_16x16x32_bf16(pa, bf2, accf[2], 0, 0, 0); \
        accf[3] = __builtin_amdgcn_mfma_f32_16x16x32_bf16(pa, bf3, accf[3], 0, 0, 0); \
    }

    STAGE(0, 0);
    __syncthreads();

    int s = 0;
    for (int st = 0; st < 16; ++st) {
        if (st < 15) STAGE(s^1, st+1);
        const unsigned long long bits = pkb[(long long)st * 2048];
        const char* wb0 = ldsbuf + s*16384 + half*8192;
        const int j0 = st * 64;
        KKBODY(0);
        KKBODY(1);
        __syncthreads();
        s ^= 1;
    }

    // ---- epilogue: combine j-halves, divide by row sum, store ----
    // last compute used buffer 1 (bytes 16384..32768): accb reuses buffer 0.
    float* accb = (float*)ldsbuf;            // [4][16][64] = 16 KB
    float* lb   = (float*)(ldsbuf + 32768);  // 64 floats
    #pragma unroll
    for (int ob = 0; ob < 4; ++ob)
        #pragma unroll
        for (int rg2 = 0; rg2 < 4; ++rg2)
            accb[(wave*16 + g*4 + rg2)*64 + ob*16 + arow] = accf[ob][rg2];
    if (arow == 0) {
        #pragma unroll
        for (int rg2 = 0; rg2 < 4; ++rg2)
            lb[wave*16 + g*4 + rg2] = accl[rg2];
    }
    __syncthreads();

    const int r  = tid >> 3;            // 0..31
    const int o0 = (tid & 7) * 8;
    const int rg = r >> 4, rl = r & 15;
    const float L   = lb[rg*16 + rl] + lb[(rg+2)*16 + rl];
    const float inv = 1.0f / L;
    float ov[8];
    #pragma unroll
    for (int k = 0; k < 8; ++k)
        ov[k] = (accb[(rg*16 + rl)*64 + o0 + k]
               + accb[((rg+2)*16 + rl)*64 + o0 + k]) * inv;
    float* op = out + (bN + i0 + r)*64 + o0;
    *(float4*)op       = (float4){ov[0], ov[1], ov[2], ov[3]};
    *(float4*)(op + 4) = (float4){ov[4], ov[5], ov[6], ov[7]};
}

// ---------------------------------------------------------------------------
// ws layout: WhT 2MB | si2 64KB | sj2 64KB | pk 4MB  (total ~6.5 MB)
// ---------------------------------------------------------------------------
extern "C" void kernel_launch(void* const* d_in, const int* in_sizes, int n_in,
                              void* d_out, int out_size, void* d_ws, size_t ws_size,
                              hipStream_t stream) {
    const float* h   = (const float*)d_in[0];
    const int*   adj = (const int*)d_in[1];
    const float* W   = (const float*)d_in[2];
    const float* a   = (const float*)d_in[3];
    float* out = (float*)d_out;

    unsigned short* WhT = (unsigned short*)d_ws;                // 2 MB
    float* si2 = (float*)((char*)d_ws + (size_t)16384*64*2);
    float* sj2 = si2 + 16384;
    unsigned long long* pkb = (unsigned long long*)(sj2 + 16384);  // 4 MB

    gat_pack<<<512, 256, 0, stream>>>(adj, pkb);
    gat_precompute<<<512, 256, 0, stream>>>(h, W, a, WhT, si2, sj2);
    gat_attention<<<512, 256, 0, stream>>>(pkb, WhT, si2, sj2, out);
}

// Round 8
// 56.221 us; speedup vs baseline: 1.1634x; 1.1634x over previous
//
#include <hip/hip_runtime.h>
#include <hip/hip_bf16.h>

#define ALPHA 0.2f
#define LOG2E 1.4426950408889634f

typedef __attribute__((ext_vector_type(8))) short bf16x8;
typedef __attribute__((ext_vector_type(4))) float f32x4;
typedef __attribute__((ext_vector_type(4))) int i32x4;

__device__ __forceinline__ int cvt_pk_bf16(float lo, float hi) {
    int r;
    asm("v_cvt_pk_bf16_f32 %0, %1, %2" : "=v"(r) : "v"(lo), "v"(hi));
    return r;
}

// async global->LDS, 16B per lane; LDS dest = wave-uniform base + lane*16
__device__ __forceinline__ void stage16(const void* g, void* l) {
    __builtin_amdgcn_global_load_lds(
        (const __attribute__((address_space(1))) void*)g,
        (__attribute__((address_space(3))) void*)l, 16, 0, 0);
}

// ---------------------------------------------------------------------------
// Kernel A (verified, unchanged): Wh = h @ W (fp32), si2/sj2 scaled by log2e,
// WhT = bf16(Wh)^T o-major [b][64][2048]. 512 blocks x 256 threads.
// ---------------------------------------------------------------------------
__global__ __launch_bounds__(256) void gat_precompute(
    const float* __restrict__ h, const float* __restrict__ W,
    const float* __restrict__ a, unsigned short* __restrict__ WhT,
    float* __restrict__ si2, float* __restrict__ sj2)
{
    __shared__ float h_lds[32][128];
    __shared__ float wh_lds[32][65];   // +1 pad
    const int tid  = threadIdx.x;
    const int lane = tid & 63;
    const int wave = tid >> 6;
    const long long row0 = (long long)blockIdx.x * 32;

    {
        const float4* s4 = (const float4*)(h + row0 * 128);
        #pragma unroll
        for (int i = 0; i < 4; ++i) {
            int idx = tid + i * 256;
            float4 v = s4[idx];
            *(float4*)&h_lds[idx >> 5][(idx & 31) * 4] = v;
        }
    }
    __syncthreads();

    const float a1 = a[lane];
    const float a2 = a[64 + lane];
    float acc[8];
    #pragma unroll
    for (int r = 0; r < 8; ++r) acc[r] = 0.0f;

    for (int f = 0; f < 128; f += 4) {
        const float w0 = W[(f+0)*64 + lane];
        const float w1 = W[(f+1)*64 + lane];
        const float w2 = W[(f+2)*64 + lane];
        const float w3 = W[(f+3)*64 + lane];
        #pragma unroll
        for (int r = 0; r < 8; ++r) {
            const float4 hv = *(const float4*)&h_lds[wave*8 + r][f];
            acc[r] = fmaf(hv.x, w0, acc[r]);
            acc[r] = fmaf(hv.y, w1, acc[r]);
            acc[r] = fmaf(hv.z, w2, acc[r]);
            acc[r] = fmaf(hv.w, w3, acc[r]);
        }
    }

    #pragma unroll
    for (int r = 0; r < 8; ++r) {
        const int rr = wave*8 + r;
        wh_lds[rr][lane] = acc[r];
        float s1 = acc[r] * a1;
        float s2 = acc[r] * a2;
        #pragma unroll
        for (int off = 32; off > 0; off >>= 1) {
            s1 += __shfl_xor(s1, off);
            s2 += __shfl_xor(s2, off);
        }
        if (lane == 0) {
            si2[row0 + rr] = s1 * LOG2E;
            sj2[row0 + rr] = s2 * LOG2E;
        }
    }
    __syncthreads();

    const long long b  = row0 >> 11;
    const int n0 = (int)(row0 & 2047);
    const int o  = tid >> 2;
    const int c0 = (tid & 3) * 8;
    i32x4 pk;
    #pragma unroll
    for (int k = 0; k < 4; ++k)
        pk[k] = cvt_pk_bf16(wh_lds[c0 + 2*k][o], wh_lds[c0 + 2*k + 1][o]);
    *(i32x4*)(WhT + (b*64 + o)*2048 + n0 + c0) = pk;
}

// ---------------------------------------------------------------------------
// Kernel B: fused masked-softmax attention (round-5 sync structure, 4x the
// occupancy). Block = (batch b = bid&7, 16-row i-tile); grid 1024 -> 4
// blocks/CU (LDS 24KB). 4 waves = (j-half = wave>>1) x (o-split = wave&1);
// 32 __syncthreads-double-buffered steps of (2 halves x 32 j).
// adj tile [16 r][16 units 16B], swizzle u = pu ^ r (inverse on SOURCE).
// Wh tile [64 o][8 units 16B] (units 0-3 half0, 4-7 half1), swizzle ^ (o&7);
// row stride 128B = 32 banks -> conflict-free frag reads (round-5 pattern).
// p = exp2(max(Ci+sj, 0.2*sj+Di)) * (adj>0), fixed row max (lrelu monotone).
// ---------------------------------------------------------------------------
__global__ __launch_bounds__(256) void gat_attention(
    const int* __restrict__ adj, const unsigned short* __restrict__ WhT,
    const float* __restrict__ si2, const float* __restrict__ sj2,
    float* __restrict__ out)
{
    __shared__ char ldsbuf[24576];   // 2 x (adj 4KB + Wh 8KB); epi reuses 8.5KB
    const int tid  = threadIdx.x;
    const int lane = tid & 63;
    const int wave = tid >> 6;
    const int b    = blockIdx.x & 7;          // batch -> XCD affinity
    const int i0   = (blockIdx.x >> 3) << 4;  // 16-row tile
    const int arow = lane & 15;
    const int g    = lane >> 4;
    const int half = wave >> 1;               // j-half (0: j<1024, 1: j>=1024)
    const int os   = wave & 1;                // o-split (o<32 / o>=32)
    const long long bN = (long long)b * 2048;

    // ---- adj staging source (1 instr/wave): lane = (r_loc<<4) | pu ----
    const int r_  = (wave << 2) + (lane >> 4);     // row 0..15
    const int pu_ = lane & 15;                     // physical 16B unit
    const int u_  = pu_ ^ r_;                      // logical unit
    const int* asrc = adj + (bN + i0 + r_)*2048 + (u_ >> 3)*1024 + (u_ & 7)*4;

    // ---- Wh staging sources (2 instr/wave): U = o*8 + p over 8KB ----
    const unsigned short* wsrc[2];
    #pragma unroll
    for (int k = 0; k < 2; ++k) {
        int U = (wave*2 + k)*64 + lane;
        int o = U >> 3, p = U & 7;
        int l = p ^ (o & 7);                       // logical unit
        wsrc[k] = WhT + ((long long)b*64 + o)*2048 + (l >> 2)*1024 + (l & 3)*8;
    }

    // ---- per-batch sjmax (block-redundant, once) ----
    const float* sjb = sj2 + bN;
    float mx = -INFINITY;
    #pragma unroll 4
    for (int i = 0; i < 32; ++i) mx = fmaxf(mx, sjb[lane + i*64]);
    #pragma unroll
    for (int off = 32; off > 0; off >>= 1) mx = fmaxf(mx, __shfl_xor(mx, off));

    const float si_r = si2[bN + i0 + arow];        // P-row = arow
    const float u0f  = si_r + mx;
    const float m2   = fmaxf(u0f, ALPHA * u0f);    // fixed row max (log2 dom)
    const float Ci   = si_r - m2;
    const float Di   = ALPHA * si_r - m2;

    f32x4 accf0 = (f32x4){0.f,0.f,0.f,0.f};
    f32x4 accf1 = (f32x4){0.f,0.f,0.f,0.f};
    f32x4 accl  = (f32x4){0.f,0.f,0.f,0.f};
    bf16x8 ones;
    #pragma unroll
    for (int k = 0; k < 8; ++k) ones[k] = (short)0x3F80;

    #define STAGE(S, STEP) { \
        const int ja = (STEP) * 32; \
        char* base = ldsbuf + (S)*12288; \
        stage16(asrc + ja,     base + wave*1024); \
        stage16(wsrc[0] + ja,  base + 4096 + wave*2048); \
        stage16(wsrc[1] + ja,  base + 4096 + wave*2048 + 1024); \
    }

    STAGE(0, 0);
    __syncthreads();

    int s = 0;
    for (int st = 0; st < 32; ++st) {
        if (st < 31) STAGE(s^1, st+1);
        const char* ab = ldsbuf + s*12288;
        const char* wb = ab + 4096;

        // B-fragments (o-major tile, conflict-free XOR pattern)
        const int o0 = os*32 + arow;               // ob = 0
        const int o1 = o0 + 16;                    // ob = 1
        const int lu = half*4 + g;                 // logical Wh unit
        const bf16x8 bf0 = *(const bf16x8*)(wb + o0*128 + (lu ^ (o0 & 7))*16);
        const bf16x8 bf1 = *(const bf16x8*)(wb + o1*128 + (lu ^ (o1 & 7))*16);

        // adj: this lane's 8 j's of row arow
        const int ua = half*8 + g*2;
        const i32x4 A0 = *(const i32x4*)(ab + arow*256 + ((ua    ) ^ arow)*16);
        const i32x4 A1 = *(const i32x4*)(ab + arow*256 + ((ua + 1) ^ arow)*16);

        const float* sjp = sjb + half*1024 + st*32 + g*8;
        const f32x4 S0 = *(const f32x4*)(sjp);
        const f32x4 S1 = *(const f32x4*)(sjp + 4);

        float p[8];
        #pragma unroll
        for (int e = 0; e < 4; ++e) {
            float pe = __builtin_amdgcn_exp2f(
                fmaxf(Ci + S0[e], fmaf(ALPHA, S0[e], Di)));
            p[e] = (A0[e] > 0) ? pe : 0.0f;
        }
        #pragma unroll
        for (int e = 0; e < 4; ++e) {
            float pe = __builtin_amdgcn_exp2f(
                fmaxf(Ci + S1[e], fmaf(ALPHA, S1[e], Di)));
            p[4+e] = (A1[e] > 0) ? pe : 0.0f;
        }
        i32x4 pk_;
        pk_[0] = cvt_pk_bf16(p[0], p[1]);
        pk_[1] = cvt_pk_bf16(p[2], p[3]);
        pk_[2] = cvt_pk_bf16(p[4], p[5]);
        pk_[3] = cvt_pk_bf16(p[6], p[7]);
        const bf16x8 pa = __builtin_bit_cast(bf16x8, pk_);

        if (os == 0)
            accl = __builtin_amdgcn_mfma_f32_16x16x32_bf16(pa, ones, accl, 0, 0, 0);
        accf0 = __builtin_amdgcn_mfma_f32_16x16x32_bf16(pa, bf0, accf0, 0, 0, 0);
        accf1 = __builtin_amdgcn_mfma_f32_16x16x32_bf16(pa, bf1, accf1, 0, 0, 0);

        __syncthreads();
        s ^= 1;
    }

    // ---- epilogue: combine j-halves, divide by row sum, store ----
    float* accb = (float*)ldsbuf;            // [2 half][16 i][64 o] = 8KB
    float* lb   = (float*)(ldsbuf + 8192);   // [2 half][16 i]
    #pragma unroll
    for (int reg = 0; reg < 4; ++reg) {
        const int irow = g*4 + reg;          // C row = i-row
        accb[(half*16 + irow)*64 + os*32 +      arow] = accf0[reg];
        accb[(half*16 + irow)*64 + os*32 + 16 + arow] = accf1[reg];
    }
    if (os == 0 && arow == 0) {
        #pragma unroll
        for (int reg = 0; reg < 4; ++reg)
            lb[half*16 + g*4 + reg] = accl[reg];
    }
    __syncthreads();

    const int r  = tid >> 4;                 // 0..15
    const int c0 = (tid & 15) * 4;
    const float L   = lb[r] + lb[16 + r];
    const float inv = 1.0f / L;
    float4 v;
    v.x = (accb[r*64 + c0 + 0] + accb[(16 + r)*64 + c0 + 0]) * inv;
    v.y = (accb[r*64 + c0 + 1] + accb[(16 + r)*64 + c0 + 1]) * inv;
    v.z = (accb[r*64 + c0 + 2] + accb[(16 + r)*64 + c0 + 2]) * inv;
    v.w = (accb[r*64 + c0 + 3] + accb[(16 + r)*64 + c0 + 3]) * inv;
    *(float4*)(out + (bN + i0 + r)*64 + c0) = v;
}

// ---------------------------------------------------------------------------
extern "C" void kernel_launch(void* const* d_in, const int* in_sizes, int n_in,
                              void* d_out, int out_size, void* d_ws, size_t ws_size,
                              hipStream_t stream) {
    const float* h   = (const float*)d_in[0];
    const int*   adj = (const int*)d_in[1];
    const float* W   = (const float*)d_in[2];
    const float* a   = (const float*)d_in[3];
    float* out = (float*)d_out;

    unsigned short* WhT = (unsigned short*)d_ws;                // 2 MB
    float* si2 = (float*)((char*)d_ws + (size_t)16384*64*2);
    float* sj2 = si2 + 16384;

    gat_precompute<<<512, 256, 0, stream>>>(h, W, a, WhT, si2, sj2);
    gat_attention<<<1024, 256, 0, stream>>>(adj, WhT, si2, sj2, out);
}

// Round 10
// 46.497 us; speedup vs baseline: 1.4067x; 1.2091x over previous
//
#include <hip/hip_runtime.h>
#include <hip/hip_bf16.h>

#define ALPHA 0.2f
#define LOG2E 1.4426950408889634f

typedef __attribute__((ext_vector_type(8))) short bf16x8;
typedef __attribute__((ext_vector_type(4))) float f32x4;
typedef __attribute__((ext_vector_type(4))) int i32x4;

__device__ __forceinline__ int cvt_pk_bf16(float lo, float hi) {
    int r;
    asm("v_cvt_pk_bf16_f32 %0, %1, %2" : "=v"(r) : "v"(lo), "v"(hi));
    return r;
}

// ---------------------------------------------------------------------------
// Kernel A (verified, unchanged): Wh = h @ W (fp32), si2/sj2 scaled by log2e,
// WhT = bf16(Wh)^T o-major [b][64][2048]. 512 blocks x 256 threads.
// ---------------------------------------------------------------------------
__global__ __launch_bounds__(256) void gat_precompute(
    const float* __restrict__ h, const float* __restrict__ W,
    const float* __restrict__ a, unsigned short* __restrict__ WhT,
    float* __restrict__ si2, float* __restrict__ sj2)
{
    __shared__ float h_lds[32][128];
    __shared__ float wh_lds[32][65];   // +1 pad
    const int tid  = threadIdx.x;
    const int lane = tid & 63;
    const int wave = tid >> 6;
    const long long row0 = (long long)blockIdx.x * 32;

    {
        const float4* s4 = (const float4*)(h + row0 * 128);
        #pragma unroll
        for (int i = 0; i < 4; ++i) {
            int idx = tid + i * 256;
            float4 v = s4[idx];
            *(float4*)&h_lds[idx >> 5][(idx & 31) * 4] = v;
        }
    }
    __syncthreads();

    const float a1 = a[lane];
    const float a2 = a[64 + lane];
    float acc[8];
    #pragma unroll
    for (int r = 0; r < 8; ++r) acc[r] = 0.0f;

    for (int f = 0; f < 128; f += 4) {
        const float w0 = W[(f+0)*64 + lane];
        const float w1 = W[(f+1)*64 + lane];
        const float w2 = W[(f+2)*64 + lane];
        const float w3 = W[(f+3)*64 + lane];
        #pragma unroll
        for (int r = 0; r < 8; ++r) {
            const float4 hv = *(const float4*)&h_lds[wave*8 + r][f];
            acc[r] = fmaf(hv.x, w0, acc[r]);
            acc[r] = fmaf(hv.y, w1, acc[r]);
            acc[r] = fmaf(hv.z, w2, acc[r]);
            acc[r] = fmaf(hv.w, w3, acc[r]);
        }
    }

    #pragma unroll
    for (int r = 0; r < 8; ++r) {
        const int rr = wave*8 + r;
        wh_lds[rr][lane] = acc[r];
        float s1 = acc[r] * a1;
        float s2 = acc[r] * a2;
        #pragma unroll
        for (int off = 32; off > 0; off >>= 1) {
            s1 += __shfl_xor(s1, off);
            s2 += __shfl_xor(s2, off);
        }
        if (lane == 0) {
            si2[row0 + rr] = s1 * LOG2E;
            sj2[row0 + rr] = s2 * LOG2E;
        }
    }
    __syncthreads();

    const long long b  = row0 >> 11;
    const int n0 = (int)(row0 & 2047);
    const int o  = tid >> 2;
    const int c0 = (tid & 3) * 8;
    i32x4 pk;
    #pragma unroll
    for (int k = 0; k < 4; ++k)
        pk[k] = cvt_pk_bf16(wh_lds[c0 + 2*k][o], wh_lds[c0 + 2*k + 1][o]);
    *(i32x4*)(WhT + (b*64 + o)*2048 + n0 + c0) = pk;
}

// ---------------------------------------------------------------------------
// Kernel B: round-5 structure (passed, 48.2us) with T14 reg-staging:
// global->VGPR loads issued at step top (NOT drained by __syncthreads --
// no LDS side-effect), consumed by ds_write after the compute phase; the
// compiler owns all waitcnt ledgers. LDS image byte-identical to round 5:
// per-lane global sources are round-5's pre-swizzled addresses, ds_write
// dest = base + lane*16 (what global_load_lds produced). Read-side swizzles
// verbatim. One __syncthreads per step. bid&7 = batch -> XCD L2 affinity.
// p = exp2(max(Ci+sj, 0.2*sj+Di)) * (adj>0), fixed row max (lrelu monotone).
// ---------------------------------------------------------------------------
__global__ __launch_bounds__(256) void gat_attention(
    const int* __restrict__ adj, const unsigned short* __restrict__ WhT,
    const float* __restrict__ si2, const float* __restrict__ sj2,
    float* __restrict__ out)
{
    __shared__ char ldsbuf[65536];   // [2][adj 16K | wh 16K]
    const int tid  = threadIdx.x;
    const int lane = tid & 63;
    const int wave = tid >> 6;
    const int b    = blockIdx.x & 7;            // batch -> XCD L2 affinity
    const int i0   = (int)((blockIdx.x >> 3) << 5);   // 32-row i-tile
    const int arow = lane & 15;
    const int g    = lane >> 4;
    const int half = wave >> 1;
    const int rgrp = wave & 1;
    const long long bN = (long long)b * 2048;

    // ---- adj load sources (round-5 pre-swizzled; lane's 16B = what
    //      global_load_lds would place at dest base + lane*16) ----
    const int* asrc[4];
    #pragma unroll
    for (int rd = 0; rd < 4; ++rd) {
        int U = (wave*4 + rd)*64 + lane;
        int r = U >> 5, pu = U & 31;
        int u = pu ^ (r & 15);                         // logical 16B unit
        int col = (u < 16) ? u*4 : (1024 + (u-16)*4);  // ints, before j0
        asrc[rd] = adj + (bN + i0 + r)*2048 + col;
    }
    // ---- WhT load sources (round-5 verbatim) ----
    const unsigned short* wsrc[4];
    #pragma unroll
    for (int rd = 0; rd < 4; ++rd) {
        int U  = wave*256 + rd*64 + lane;
        int hf = U >> 9;
        int o  = (U & 511) >> 3;
        int pu = U & 7;
        wsrc[rd] = WhT + ((long long)b*64 + o)*2048 + hf*1024
                       + ((pu ^ (o & 7)) * 8);
    }

    // ---- per-batch sjmax (block-redundant, once) ----
    const float* sjb = sj2 + bN;
    float mx = -INFINITY;
    #pragma unroll 4
    for (int i = 0; i < 32; ++i) mx = fmaxf(mx, sjb[lane + i*64]);
    #pragma unroll
    for (int off = 32; off > 0; off >>= 1) mx = fmaxf(mx, __shfl_xor(mx, off));

    const float si_r = si2[bN + i0 + rgrp*16 + arow];
    const float u0f  = si_r + mx;
    const float m2   = fmaxf(u0f, ALPHA * u0f);     // fixed row max (log2 dom)
    const float Ci   = si_r - m2;
    const float Di   = ALPHA * si_r - m2;
    const int   rr   = rgrp*16 + arow;              // adj tile row

    f32x4 accf[4];
    #pragma unroll
    for (int ob = 0; ob < 4; ++ob) accf[ob] = (f32x4){0.f,0.f,0.f,0.f};
    f32x4 accl = (f32x4){0.f,0.f,0.f,0.f};
    bf16x8 ones;
    #pragma unroll
    for (int k = 0; k < 8; ++k) ones[k] = (short)0x3F80;

    // staging registers (named, constant-indexed -- rule #20)
    i32x4 a0_, a1_, a2_, a3_, w0_, w1_, w2_, w3_;

    #define LOADREGS(STEP) { \
        const int ja = (STEP) * 64; \
        a0_ = *(const i32x4*)(asrc[0] + ja); \
        a1_ = *(const i32x4*)(asrc[1] + ja); \
        a2_ = *(const i32x4*)(asrc[2] + ja); \
        a3_ = *(const i32x4*)(asrc[3] + ja); \
        w0_ = *(const i32x4*)(wsrc[0] + ja); \
        w1_ = *(const i32x4*)(wsrc[1] + ja); \
        w2_ = *(const i32x4*)(wsrc[2] + ja); \
        w3_ = *(const i32x4*)(wsrc[3] + ja); \
    }

    #define WRITEREGS(S) { \
        char* aw = ldsbuf + (S)*32768 + wave*4096 + lane*16; \
        *(i32x4*)(aw)        = a0_; \
        *(i32x4*)(aw + 1024) = a1_; \
        *(i32x4*)(aw + 2048) = a2_; \
        *(i32x4*)(aw + 3072) = a3_; \
        char* ww = aw + 16384; \
        *(i32x4*)(ww)        = w0_; \
        *(i32x4*)(ww + 1024) = w1_; \
        *(i32x4*)(ww + 2048) = w2_; \
        *(i32x4*)(ww + 3072) = w3_; \
    }

    #define KKBODY(KK) { \
        const char* wb = ab + 16384 + half*8192; \
        const int ws = ((KK)*4 + g) ^ (arow & 7); \
        const bf16x8 bf0 = *(const bf16x8*)(wb + (( 0 + arow)*8 + ws)*16); \
        const bf16x8 bf1 = *(const bf16x8*)(wb + ((16 + arow)*8 + ws)*16); \
        const bf16x8 bf2 = *(const bf16x8*)(wb + ((32 + arow)*8 + ws)*16); \
        const bf16x8 bf3 = *(const bf16x8*)(wb + ((48 + arow)*8 + ws)*16); \
        const int u0a = half*16 + (KK)*8 + g*2; \
        const i32x4 A0 = *(const i32x4*)(ab + rr*512 + ((u0a    ) ^ arow)*16); \
        const i32x4 A1 = *(const i32x4*)(ab + rr*512 + ((u0a + 1) ^ arow)*16); \
        const float* sjp = sjb + half*1024 + j0 + (KK)*32 + g*8; \
        const f32x4 S0 = *(const f32x4*)(sjp); \
        const f32x4 S1 = *(const f32x4*)(sjp + 4); \
        float p[8]; \
        _Pragma("unroll") \
        for (int e = 0; e < 4; ++e) { \
            float pe = __builtin_amdgcn_exp2f( \
                fmaxf(Ci + S0[e], fmaf(ALPHA, S0[e], Di))); \
            p[e] = (A0[e] > 0) ? pe : 0.0f; \
        } \
        _Pragma("unroll") \
        for (int e = 0; e < 4; ++e) { \
            float pe = __builtin_amdgcn_exp2f( \
                fmaxf(Ci + S1[e], fmaf(ALPHA, S1[e], Di))); \
            p[4+e] = (A1[e] > 0) ? pe : 0.0f; \
        } \
        i32x4 pk_; \
        pk_[0] = cvt_pk_bf16(p[0], p[1]); \
        pk_[1] = cvt_pk_bf16(p[2], p[3]); \
        pk_[2] = cvt_pk_bf16(p[4], p[5]); \
        pk_[3] = cvt_pk_bf16(p[6], p[7]); \
        const bf16x8 pa = __builtin_bit_cast(bf16x8, pk_); \
        accl    = __builtin_amdgcn_mfma_f32_16x16x32_bf16(pa, ones, accl, 0, 0, 0); \
        accf[0] = __builtin_amdgcn_mfma_f32_16x16x32_bf16(pa, bf0, accf[0], 0, 0, 0); \
        accf[1] = __builtin_amdgcn_mfma_f32_16x16x32_bf16(pa, bf1, accf[1], 0, 0, 0); \
        accf[2] = __builtin_amdgcn_mfma_f32_16x16x32_bf16(pa, bf2, accf[2], 0, 0, 0); \
        accf[3] = __builtin_amdgcn_mfma_f32_16x16x32_bf16(pa, bf3, accf[3], 0, 0, 0); \
    }

    // ---- prologue: fill buffer 0 ----
    LOADREGS(0);
    WRITEREGS(0);
    __syncthreads();

    // ---- main loop: one barrier per step; prefetch lives in VGPRs ----
    int s = 0;
    for (int st = 0; st < 15; ++st) {
        LOADREGS(st + 1);                    // issue early (regs, not LDS)
        const char* ab = ldsbuf + s*32768;
        const int j0 = st * 64;
        KKBODY(0);                           // compute hides load latency
        KKBODY(1);
        WRITEREGS(s^1);                      // counted vmcnt inserted here
        __syncthreads();                     // buf s^1 published
        s ^= 1;
    }
    {   // last step (no prefetch)
        const char* ab = ldsbuf + s*32768;   // s = 1
        const int j0 = 15 * 64;
        KKBODY(0);
        KKBODY(1);
    }

    // ---- epilogue: combine j-halves, divide by row sum, store ----
    // last compute used buffer 1; buffer 0 (read last at step 14, barriered)
    // is reused for the combine.
    float* accb = (float*)ldsbuf;            // [4][16][64] = 16 KB
    float* lb   = (float*)(ldsbuf + 16384);  // [4][16]
    #pragma unroll
    for (int ob = 0; ob < 4; ++ob)
        #pragma unroll
        for (int rg2 = 0; rg2 < 4; ++rg2)
            accb[(wave*16 + g*4 + rg2)*64 + ob*16 + arow] = accf[ob][rg2];
    if (arow == 0) {
        #pragma unroll
        for (int rg2 = 0; rg2 < 4; ++rg2)
            lb[wave*16 + g*4 + rg2] = accl[rg2];
    }
    __syncthreads();

    const int r  = tid >> 3;            // 0..31
    const int o0 = (tid & 7) * 8;
    const int rg = r >> 4, rl = r & 15;
    const float L   = lb[rg*16 + rl] + lb[(rg+2)*16 + rl];
    const float inv = 1.0f / L;
    float ov[8];
    #pragma unroll
    for (int k = 0; k < 8; ++k)
        ov[k] = (accb[(rg*16 + rl)*64 + o0 + k]
               + accb[((rg+2)*16 + rl)*64 + o0 + k]) * inv;
    float* op = out + (bN + i0 + r)*64 + o0;
    *(float4*)op       = (float4){ov[0], ov[1], ov[2], ov[3]};
    *(float4*)(op + 4) = (float4){ov[4], ov[5], ov[6], ov[7]};
}

// ---------------------------------------------------------------------------
extern "C" void kernel_launch(void* const* d_in, const int* in_sizes, int n_in,
                              void* d_out, int out_size, void* d_ws, size_t ws_size,
                              hipStream_t stream) {
    const float* h   = (const float*)d_in[0];
    const int*   adj = (const int*)d_in[1];
    const float* W   = (const float*)d_in[2];
    const float* a   = (const float*)d_in[3];
    float* out = (float*)d_out;

    unsigned short* WhT = (unsigned short*)d_ws;                // 2 MB
    float* si2 = (float*)((char*)d_ws + (size_t)16384*64*2);
    float* sj2 = si2 + 16384;

    gat_precompute<<<512, 256, 0, stream>>>(h, W, a, WhT, si2, sj2);
    gat_attention<<<512, 256, 0, stream>>>(adj, WhT, si2, sj2, out);
}

// Round 11
// 45.224 us; speedup vs baseline: 1.4463x; 1.0282x over previous
//
#include <hip/hip_runtime.h>
#include <hip/hip_bf16.h>

#define ALPHA 0.2f
#define LOG2E 1.4426950408889634f

typedef __attribute__((ext_vector_type(8))) short bf16x8;
typedef __attribute__((ext_vector_type(4))) float f32x4;
typedef __attribute__((ext_vector_type(4))) int i32x4;

__device__ __forceinline__ int cvt_pk_bf16(float lo, float hi) {
    int r;
    asm("v_cvt_pk_bf16_f32 %0, %1, %2" : "=v"(r) : "v"(lo), "v"(hi));
    return r;
}

// async global->LDS, 16B per lane; LDS dest = wave-uniform base + lane*16
__device__ __forceinline__ void stage16(const void* g, void* l) {
    __builtin_amdgcn_global_load_lds(
        (const __attribute__((address_space(1))) void*)g,
        (__attribute__((address_space(3))) void*)l, 16, 0, 0);
}

// ---------------------------------------------------------------------------
// Kernel A: Wh = h @ W (fp32), si2/sj2 scaled by log2e, and Wh emitted
// PRE-FRAGMENTED for the MFMA B operand:
//   WhF[((b*64 + jc)*4 + ob)*512 + lane*8 + e] = bf16(Wh[j][o]),
//   j = jc*32 + (lane>>4)*8 + e, o = ob*16 + (lane&15)
// so kernel B's B-fragment load is one coalesced dwordx4 per lane.
// 512 blocks x 256 threads, 32 n-rows (= exactly one j-chunk) per block.
// ---------------------------------------------------------------------------
__global__ __launch_bounds__(256) void gat_precompute(
    const float* __restrict__ h, const float* __restrict__ W,
    const float* __restrict__ a, unsigned short* __restrict__ WhF,
    float* __restrict__ si2, float* __restrict__ sj2)
{
    __shared__ float h_lds[32][128];
    __shared__ float wh_lds[32][65];   // +1 pad
    const int tid  = threadIdx.x;
    const int lane = tid & 63;
    const int wave = tid >> 6;
    const long long row0 = (long long)blockIdx.x * 32;

    {
        const float4* s4 = (const float4*)(h + row0 * 128);
        #pragma unroll
        for (int i = 0; i < 4; ++i) {
            int idx = tid + i * 256;
            float4 v = s4[idx];
            *(float4*)&h_lds[idx >> 5][(idx & 31) * 4] = v;
        }
    }
    __syncthreads();

    const float a1 = a[lane];
    const float a2 = a[64 + lane];
    float acc[8];
    #pragma unroll
    for (int r = 0; r < 8; ++r) acc[r] = 0.0f;

    for (int f = 0; f < 128; f += 4) {
        const float w0 = W[(f+0)*64 + lane];
        const float w1 = W[(f+1)*64 + lane];
        const float w2 = W[(f+2)*64 + lane];
        const float w3 = W[(f+3)*64 + lane];
        #pragma unroll
        for (int r = 0; r < 8; ++r) {
            const float4 hv = *(const float4*)&h_lds[wave*8 + r][f];
            acc[r] = fmaf(hv.x, w0, acc[r]);
            acc[r] = fmaf(hv.y, w1, acc[r]);
            acc[r] = fmaf(hv.z, w2, acc[r]);
            acc[r] = fmaf(hv.w, w3, acc[r]);
        }
    }

    #pragma unroll
    for (int r = 0; r < 8; ++r) {
        const int rr = wave*8 + r;
        wh_lds[rr][lane] = acc[r];
        float s1 = acc[r] * a1;
        float s2 = acc[r] * a2;
        #pragma unroll
        for (int off = 32; off > 0; off >>= 1) {
            s1 += __shfl_xor(s1, off);
            s2 += __shfl_xor(s2, off);
        }
        if (lane == 0) {
            si2[row0 + rr] = s1 * LOG2E;
            sj2[row0 + rr] = s2 * LOG2E;
        }
    }
    __syncthreads();

    // fragment write: tid = ob*64 + lane
    const long long b  = row0 >> 11;
    const int jcb  = (int)((row0 & 2047) >> 5);   // j-chunk within batch
    const int ob   = tid >> 6;
    const int ln   = tid & 63;
    const int ar   = ln & 15;
    const int gg   = ln >> 4;
    i32x4 pk;
    #pragma unroll
    for (int k = 0; k < 4; ++k)
        pk[k] = cvt_pk_bf16(wh_lds[gg*8 + 2*k    ][ob*16 + ar],
                            wh_lds[gg*8 + 2*k + 1][ob*16 + ar]);
    *(i32x4*)(WhF + ((b*64 + jcb)*4 + ob)*512 + ln*8) = pk;
}

// ---------------------------------------------------------------------------
// Kernel B: fused masked-softmax attention.
//  - Block = (batch b = bid&7 -> XCD L2 affinity, 16-row i-tile); grid 1024
//    -> 4 blocks/CU (LDS 16.6KB), 16 waves/CU.
//  - 4 waves = private 512-j quarters, swept in 16 dbuf steps of 32 j.
//  - adj: round-5-proven global_load_lds staging (2KB/wave/step, source-side
//    XOR u^(r&7), read-side same XOR; 2-way residual conflicts = free).
//  - Wh: NO LDS -- B-fragments loaded straight from pre-fragmented global
//    (coalesced 1KB/fragment, L2-resident), prefetched one step ahead in regs.
//  - p = exp2(max(Ci+sj, 0.2*sj+Di)) * (adj>0), fixed row max (lrelu mono).
// ---------------------------------------------------------------------------
__global__ __launch_bounds__(256, 4) void gat_attention(
    const int* __restrict__ adj, const unsigned short* __restrict__ WhF,
    const float* __restrict__ si2, const float* __restrict__ sj2,
    float* __restrict__ out)
{
    __shared__ char ldsbuf[16640];   // 2 x 8KB adj dbuf; epi: accb 16K + lb
    const int tid  = threadIdx.x;
    const int lane = tid & 63;
    const int wave = tid >> 6;
    const int b    = blockIdx.x & 7;                 // batch -> XCD affinity
    const int i0   = (int)((blockIdx.x >> 3) << 4);  // 16-row i-tile
    const int arow = lane & 15;
    const int g    = lane >> 4;
    const long long bN = (long long)b * 2048;

    // ---- adj staging sources (pre-swizzled: slot pu holds unit pu^(r&7)) --
    const int* asrc0;
    const int* asrc1;
    {
        int r = lane >> 3;
        int u = (lane & 7) ^ (r & 7);
        asrc0 = adj + (bN + i0 + r)*2048 + wave*512 + u*4;
        int r2 = 8 + (lane >> 3);
        int u2 = (lane & 7) ^ (r2 & 7);
        asrc1 = adj + (bN + i0 + r2)*2048 + wave*512 + u2*4;
    }

    // ---- B-fragment base: frag (st, ob) at fbase + (st*4 + ob)*512 ----
    const unsigned short* fbase =
        WhF + ((long long)(b*64 + wave*16) * 4) * 512 + lane*8;

    // ---- per-batch sjmax (block-redundant, once) ----
    const float* sjb = sj2 + bN;
    float mx = -INFINITY;
    #pragma unroll 4
    for (int i = 0; i < 32; ++i) mx = fmaxf(mx, sjb[lane + i*64]);
    #pragma unroll
    for (int off = 32; off > 0; off >>= 1) mx = fmaxf(mx, __shfl_xor(mx, off));

    const float si_r = si2[bN + i0 + arow];        // P-row = arow
    const float u0f  = si_r + mx;
    const float m2   = fmaxf(u0f, ALPHA * u0f);    // fixed row max (log2 dom)
    const float Ci   = si_r - m2;
    const float Di   = ALPHA * si_r - m2;

    const float* sjq = sjb + wave*512 + g*8;       // this lane's sj stream

    f32x4 accf[4];
    #pragma unroll
    for (int ob = 0; ob < 4; ++ob) accf[ob] = (f32x4){0.f,0.f,0.f,0.f};
    f32x4 accl = (f32x4){0.f,0.f,0.f,0.f};
    bf16x8 ones;
    #pragma unroll
    for (int k = 0; k < 8; ++k) ones[k] = (short)0x3F80;   // bf16 1.0

    bf16x8 cb0, cb1, cb2, cb3, nb0, nb1, nb2, nb3;

    #define STAGE(S, STEP) { \
        char* base_ = ldsbuf + (S)*8192 + wave*2048; \
        stage16(asrc0 + (STEP)*32, base_); \
        stage16(asrc1 + (STEP)*32, base_ + 1024); \
    }

    #define LOADB(D0, D1, D2, D3, STEP) { \
        D0 = *(const bf16x8*)(fbase + ((STEP)*4 + 0)*512); \
        D1 = *(const bf16x8*)(fbase + ((STEP)*4 + 1)*512); \
        D2 = *(const bf16x8*)(fbase + ((STEP)*4 + 2)*512); \
        D3 = *(const bf16x8*)(fbase + ((STEP)*4 + 3)*512); \
    }

    #define BODY(S, STEP) { \
        const char* ab = ldsbuf + (S)*8192 + wave*2048; \
        const i32x4 A0 = *(const i32x4*)(ab + arow*128 + ((g*2    ) ^ (arow & 7))*16); \
        const i32x4 A1 = *(const i32x4*)(ab + arow*128 + ((g*2 + 1) ^ (arow & 7))*16); \
        const f32x4 S0 = *(const f32x4*)(sjq + (STEP)*32); \
        const f32x4 S1 = *(const f32x4*)(sjq + (STEP)*32 + 4); \
        float p[8]; \
        _Pragma("unroll") \
        for (int e = 0; e < 4; ++e) { \
            float pe = __builtin_amdgcn_exp2f( \
                fmaxf(Ci + S0[e], fmaf(ALPHA, S0[e], Di))); \
            p[e] = (A0[e] > 0) ? pe : 0.0f; \
        } \
        _Pragma("unroll") \
        for (int e = 0; e < 4; ++e) { \
            float pe = __builtin_amdgcn_exp2f( \
                fmaxf(Ci + S1[e], fmaf(ALPHA, S1[e], Di))); \
            p[4+e] = (A1[e] > 0) ? pe : 0.0f; \
        } \
        i32x4 pk_; \
        pk_[0] = cvt_pk_bf16(p[0], p[1]); \
        pk_[1] = cvt_pk_bf16(p[2], p[3]); \
        pk_[2] = cvt_pk_bf16(p[4], p[5]); \
        pk_[3] = cvt_pk_bf16(p[6], p[7]); \
        const bf16x8 pa = __builtin_bit_cast(bf16x8, pk_); \
        accl    = __builtin_amdgcn_mfma_f32_16x16x32_bf16(pa, ones, accl,    0, 0, 0); \
        accf[0] = __builtin_amdgcn_mfma_f32_16x16x32_bf16(pa, cb0, accf[0], 0, 0, 0); \
        accf[1] = __builtin_amdgcn_mfma_f32_16x16x32_bf16(pa, cb1, accf[1], 0, 0, 0); \
        accf[2] = __builtin_amdgcn_mfma_f32_16x16x32_bf16(pa, cb2, accf[2], 0, 0, 0); \
        accf[3] = __builtin_amdgcn_mfma_f32_16x16x32_bf16(pa, cb3, accf[3], 0, 0, 0); \
    }

    // ---- prologue ----
    STAGE(0, 0);
    LOADB(cb0, cb1, cb2, cb3, 0);
    __syncthreads();

    // ---- main loop: one barrier/step; B-frags prefetched in regs ----
    int s = 0;
    for (int st = 0; st < 15; ++st) {
        STAGE(s^1, st+1);
        LOADB(nb0, nb1, nb2, nb3, st+1);
        BODY(s, st);
        __syncthreads();
        cb0 = nb0; cb1 = nb1; cb2 = nb2; cb3 = nb3;
        s ^= 1;
    }
    BODY(s, 15);

    // ---- epilogue: combine the 4 j-quarter partials, divide, store ----
    __syncthreads();                          // all waves done with adj bufs
    float* accb = (float*)ldsbuf;             // [4 wave][16 i][64 o] = 16KB
    float* lb   = (float*)(ldsbuf + 16384);   // [4 wave][16 i]
    #pragma unroll
    for (int ob = 0; ob < 4; ++ob)
        #pragma unroll
        for (int reg = 0; reg < 4; ++reg)
            accb[(wave*16 + g*4 + reg)*64 + ob*16 + arow] = accf[ob][reg];
    if (arow == 0) {
        #pragma unroll
        for (int reg = 0; reg < 4; ++reg)
            lb[wave*16 + g*4 + reg] = accl[reg];
    }
    __syncthreads();

    const int r  = tid >> 4;                  // 0..15
    const int c0 = (tid & 15) * 4;
    const float L = lb[r] + lb[16 + r] + lb[32 + r] + lb[48 + r];
    const float inv = 1.0f / L;
    float4 v;
    v.x = (accb[r*64 + c0 + 0] + accb[(16+r)*64 + c0 + 0]
         + accb[(32+r)*64 + c0 + 0] + accb[(48+r)*64 + c0 + 0]) * inv;
    v.y = (accb[r*64 + c0 + 1] + accb[(16+r)*64 + c0 + 1]
         + accb[(32+r)*64 + c0 + 1] + accb[(48+r)*64 + c0 + 1]) * inv;
    v.z = (accb[r*64 + c0 + 2] + accb[(16+r)*64 + c0 + 2]
         + accb[(32+r)*64 + c0 + 2] + accb[(48+r)*64 + c0 + 2]) * inv;
    v.w = (accb[r*64 + c0 + 3] + accb[(16+r)*64 + c0 + 3]
         + accb[(32+r)*64 + c0 + 3] + accb[(48+r)*64 + c0 + 3]) * inv;
    *(float4*)(out + (bN + i0 + r)*64 + c0) = v;
}

// ---------------------------------------------------------------------------
// ws layout: WhF 2MB | si2 64KB | sj2 64KB
// ---------------------------------------------------------------------------
extern "C" void kernel_launch(void* const* d_in, const int* in_sizes, int n_in,
                              void* d_out, int out_size, void* d_ws, size_t ws_size,
                              hipStream_t stream) {
    const float* h   = (const float*)d_in[0];
    const int*   adj = (const int*)d_in[1];
    const float* W   = (const float*)d_in[2];
    const float* a   = (const float*)d_in[3];
    float* out = (float*)d_out;

    unsigned short* WhF = (unsigned short*)d_ws;                // 2 MB
    float* si2 = (float*)((char*)d_ws + (size_t)16384*64*2);
    float* sj2 = si2 + 16384;

    gat_precompute<<<512, 256, 0, stream>>>(h, W, a, WhF, si2, sj2);
    gat_attention<<<1024, 256, 0, stream>>>(adj, WhF, si2, sj2, out);
}